// Round 8
// baseline (429.649 us; speedup 1.0000x reference)
//
#include <hip/hip_runtime.h>
#include <math.h>

// Problem: N=8192 nodes, D=256 features, H=64 hidden.
// out = [h_out (N*D floats), e (N floats)] concatenated, fp32.
// ws layout: g (N*256 bf16 = 4 MB) | masks (N * 32 groups * 4 u64 = 8 MB)

typedef float nfloat4 __attribute__((ext_vector_type(4)));

__device__ inline float bf16_to_f32(unsigned short s) {
    union { unsigned u; float f; } c; c.u = ((unsigned)s) << 16; return c.f;
}
__device__ inline unsigned short f32_to_bf16(float f) {   // RNE, finite inputs
    union { float f; unsigned u; } c; c.f = f;
    unsigned r = c.u + 0x7FFFu + ((c.u >> 16) & 1u);
    return (unsigned short)(r >> 16);
}

// ---------------- Kernel 1: gate + bf16 pre-scale ----------------------------
__global__ __launch_bounds__(256) void gate_kernel(const float* __restrict__ h,
                                                   const float* __restrict__ W1,
                                                   const float* __restrict__ b1,
                                                   const float* __restrict__ W2,
                                                   const float* __restrict__ b2,
                                                   float* __restrict__ e_out,
                                                   unsigned short* __restrict__ g_out,
                                                   int N) {
    __shared__ float W1s[256 * 64];            // 64 KB
    const int tid = threadIdx.x;

    const float4* W1v = reinterpret_cast<const float4*>(W1);
    float4* W1sv = reinterpret_cast<float4*>(W1s);
    #pragma unroll
    for (int t = 0; t < 16; ++t) W1sv[tid + 256 * t] = W1v[tid + 256 * t];
    __syncthreads();

    const int wave = tid >> 6;
    const int k    = tid & 63;
    const float b1k = b1[k];
    const float w2k = W2[k];
    const float b2v = b2[0];

    const int base = blockIdx.x * 16;
    for (int r = wave; r < 16; r += 4) {
        const int i = base + r;
        if (i >= N) break;
        const float4* hv = reinterpret_cast<const float4*>(h + (size_t)i * 256);
        float acc = 0.f;
        #pragma unroll 4
        for (int d4 = 0; d4 < 64; ++d4) {
            float4 a = hv[d4];
            const int d = d4 * 4;
            acc = fmaf(a.x, W1s[(d + 0) * 64 + k], acc);
            acc = fmaf(a.y, W1s[(d + 1) * 64 + k], acc);
            acc = fmaf(a.z, W1s[(d + 2) * 64 + k], acc);
            acc = fmaf(a.w, W1s[(d + 3) * 64 + k], acc);
        }
        float v = fmaxf(acc + b1k, 0.f) * w2k;
        #pragma unroll
        for (int off = 32; off > 0; off >>= 1) v += __shfl_down(v, off);
        float vs = __shfl(v, 0);
        float ev = 1.f / (1.f + expf(-(vs + b2v)));
        if (k == 0) e_out[i] = ev;
        float4 hr = hv[k];
        ushort4 p;
        p.x = f32_to_bf16(ev * hr.x);
        p.y = f32_to_bf16(ev * hr.y);
        p.z = f32_to_bf16(ev * hr.z);
        p.w = f32_to_bf16(ev * hr.w);
        reinterpret_cast<ushort4*>(g_out + (size_t)i * 256)[k] = p;
    }
}

// ---------------- Kernel 2a: near-pure A-stream -> nonzero bitmasks ----------
// Wave per row, prefetch depth 4. Per 256-col group: 4 cmps + 4 ballots +
// ONE 32-B store (lanes 0-3 write the four u64 masks). No prefix-popcount,
// no scattered conditional stores — minimal non-stream work.
__global__ __launch_bounds__(256) void scan_kernel(const float* __restrict__ A,
                                                   unsigned long long* __restrict__ masks,
                                                   int N) {
    const int tid  = threadIdx.x;
    const int lane = tid & 63;
    const int i    = blockIdx.x * 4 + (tid >> 6);
    if (i >= N) return;

    const int groups = N / 256;                 // 32
    const nfloat4* Arow = reinterpret_cast<const nfloat4*>(A + (size_t)i * N);
    unsigned long long* mrow = masks + (size_t)i * groups * 4;

    nfloat4 q0 = __builtin_nontemporal_load(&Arow[0 * 64 + lane]);
    nfloat4 q1 = __builtin_nontemporal_load(&Arow[1 * 64 + lane]);
    nfloat4 q2 = __builtin_nontemporal_load(&Arow[2 * 64 + lane]);
    nfloat4 q3 = __builtin_nontemporal_load(&Arow[3 * 64 + lane]);

    for (int gi = 0; gi < groups; gi += 4) {
        nfloat4 c0 = q0, c1 = q1, c2 = q2, c3 = q3;
        if (gi + 4 < groups) {
            q0 = __builtin_nontemporal_load(&Arow[(gi + 4) * 64 + lane]);
            q1 = __builtin_nontemporal_load(&Arow[(gi + 5) * 64 + lane]);
            q2 = __builtin_nontemporal_load(&Arow[(gi + 6) * 64 + lane]);
            q3 = __builtin_nontemporal_load(&Arow[(gi + 7) * 64 + lane]);
        }
        #pragma unroll
        for (int u = 0; u < 4; ++u) {
            nfloat4 a4 = (u == 0) ? c0 : (u == 1) ? c1 : (u == 2) ? c2 : c3;
            unsigned long long mx = __ballot(a4.x > 0.f);
            unsigned long long my = __ballot(a4.y > 0.f);
            unsigned long long mz = __ballot(a4.z > 0.f);
            unsigned long long mw = __ballot(a4.w > 0.f);
            unsigned long long mv = (lane == 0) ? mx : (lane == 1) ? my
                                   : (lane == 2) ? mz : mw;
            if (lane < 4) mrow[(gi + u) * 4 + lane] = mv;   // one 32-B transaction
        }
    }
}

// ---------------- Kernel 2b: gather via masks --------------------------------
// Wave per row; iterate the stored 256-col masks; 4-wide interleaved bf16
// g-row gathers (wave-uniform branches). Mask quad prefetched 1 group ahead.
__global__ __launch_bounds__(256) void gather_kernel(const unsigned long long* __restrict__ masks,
                                                     const unsigned short* __restrict__ g,
                                                     float* __restrict__ h_out,
                                                     int N) {
    const int tid  = threadIdx.x;
    const int lane = tid & 63;
    const int i    = blockIdx.x * 4 + (tid >> 6);
    if (i >= N) return;

    const int groups = N / 256;                 // 32
    const ushort4* gv = reinterpret_cast<const ushort4*>(g);
    const unsigned long long* mrow = masks + (size_t)i * groups * 4;

    float4 acc = {0.f, 0.f, 0.f, 0.f};

    unsigned long long nx = mrow[0], ny = mrow[1], nz = mrow[2], nw = mrow[3];
    for (int gi = 0; gi < groups; ++gi) {
        unsigned long long mx = nx, my = ny, mz = nz, mw = nw;
        if (gi + 1 < groups) {
            nx = mrow[(gi + 1) * 4 + 0];
            ny = mrow[(gi + 1) * 4 + 1];
            nz = mrow[(gi + 1) * 4 + 2];
            nw = mrow[(gi + 1) * 4 + 3];
        }
        const int jb = gi * 256;

        while (mx | my | mz | mw) {
            ushort4 ux, uy, uz, uw;
            bool px = mx != 0, py = my != 0, pz = mz != 0, pw = mw != 0;
            if (px) { int b = __builtin_ctzll(mx); mx &= mx - 1;
                      ux = gv[(size_t)(jb + 4 * b + 0) * 64 + lane]; }
            if (py) { int b = __builtin_ctzll(my); my &= my - 1;
                      uy = gv[(size_t)(jb + 4 * b + 1) * 64 + lane]; }
            if (pz) { int b = __builtin_ctzll(mz); mz &= mz - 1;
                      uz = gv[(size_t)(jb + 4 * b + 2) * 64 + lane]; }
            if (pw) { int b = __builtin_ctzll(mw); mw &= mw - 1;
                      uw = gv[(size_t)(jb + 4 * b + 3) * 64 + lane]; }
            if (px) { acc.x += bf16_to_f32(ux.x); acc.y += bf16_to_f32(ux.y);
                      acc.z += bf16_to_f32(ux.z); acc.w += bf16_to_f32(ux.w); }
            if (py) { acc.x += bf16_to_f32(uy.x); acc.y += bf16_to_f32(uy.y);
                      acc.z += bf16_to_f32(uy.z); acc.w += bf16_to_f32(uy.w); }
            if (pz) { acc.x += bf16_to_f32(uz.x); acc.y += bf16_to_f32(uz.y);
                      acc.z += bf16_to_f32(uz.z); acc.w += bf16_to_f32(uz.w); }
            if (pw) { acc.x += bf16_to_f32(uw.x); acc.y += bf16_to_f32(uw.y);
                      acc.z += bf16_to_f32(uw.z); acc.w += bf16_to_f32(uw.w); }
        }
    }

    nfloat4 r; r.x = acc.x; r.y = acc.y; r.z = acc.z; r.w = acc.w;
    nfloat4* outv = reinterpret_cast<nfloat4*>(h_out + (size_t)i * 256);
    __builtin_nontemporal_store(r, &outv[lane]);
}

extern "C" void kernel_launch(void* const* d_in, const int* in_sizes, int n_in,
                              void* d_out, int out_size, void* d_ws, size_t ws_size,
                              hipStream_t stream) {
    const float* A  = (const float*)d_in[0];   // [N, N]
    const float* h  = (const float*)d_in[1];   // [N, D]
    const float* W1 = (const float*)d_in[2];   // [D, H]
    const float* b1 = (const float*)d_in[3];   // [H]
    const float* W2 = (const float*)d_in[4];   // [H, 1]
    const float* b2 = (const float*)d_in[5];   // [1]

    const int H = in_sizes[3];                 // 64
    const int D = in_sizes[2] / H;             // 256
    const int N = in_sizes[1] / D;             // 8192

    float* out   = (float*)d_out;
    float* h_out = out;                        // N*D
    float* e_out = out + (size_t)N * D;        // N

    unsigned char* ws = (unsigned char*)d_ws;
    unsigned short* g_buf = (unsigned short*)ws;                            // 4 MB
    unsigned long long* mask_buf =
        (unsigned long long*)(ws + (size_t)N * D * 2);                      // 8 MB

    scan_kernel<<<(N + 3) / 4, 256, 0, stream>>>(A, mask_buf, N);
    gate_kernel<<<(N + 15) / 16, 256, 0, stream>>>(h, W1, b1, W2, b2, e_out, g_buf, N);
    gather_kernel<<<(N + 3) / 4, 256, 0, stream>>>(mask_buf, g_buf, h_out, N);
}